// Round 1
// baseline (1128.651 us; speedup 1.0000x reference)
//
#include <hip/hip_runtime.h>

#define D 256
#define BM 32
#define BK 32
#define XS_PITCH 36  // BK+4: keeps float4 alignment, breaks pow2 stride

// ---------------- GEMM: support = X @ W  (fp32, LDS-tiled) ----------------
__global__ __launch_bounds__(256) void gemm_kernel(const float* __restrict__ X,
                                                   const float* __restrict__ W,
                                                   float* __restrict__ S, int N) {
    __shared__ float Ws[BK * D];        // 32 KB
    __shared__ float Xs[BM * XS_PITCH]; // 4.5 KB

    const int t    = threadIdx.x;
    const int c    = t & 63;   // column group: cols c*4 .. c*4+3
    const int rg   = t >> 6;   // row group: rows rg*8 .. rg*8+7
    const int row0 = blockIdx.x * BM;

    float acc[8][4];
#pragma unroll
    for (int i = 0; i < 8; i++) {
        acc[i][0] = 0.f; acc[i][1] = 0.f; acc[i][2] = 0.f; acc[i][3] = 0.f;
    }

    const int xr = t >> 3;        // 0..31 (row within tile)
    const int xk = (t & 7) * 4;   // 0..28 (k within tile)
    const int xrow = min(row0 + xr, N - 1);  // clamp for tail safety

    for (int kt = 0; kt < D; kt += BK) {
        // stage W tile [BK][D] — coalesced
#pragma unroll
        for (int i = 0; i < BK; i++)
            Ws[i * D + t] = W[(kt + i) * D + t];
        // stage X tile [BM][BK] — float4 loads
        float4 xv = *reinterpret_cast<const float4*>(&X[(size_t)xrow * D + kt + xk]);
        Xs[xr * XS_PITCH + xk + 0] = xv.x;
        Xs[xr * XS_PITCH + xk + 1] = xv.y;
        Xs[xr * XS_PITCH + xk + 2] = xv.z;
        Xs[xr * XS_PITCH + xk + 3] = xv.w;
        __syncthreads();

#pragma unroll
        for (int k4 = 0; k4 < BK; k4 += 4) {
            float xs[8][4];
#pragma unroll
            for (int i = 0; i < 8; i++) {
                float4 x4 = *reinterpret_cast<const float4*>(&Xs[(rg * 8 + i) * XS_PITCH + k4]);
                xs[i][0] = x4.x; xs[i][1] = x4.y; xs[i][2] = x4.z; xs[i][3] = x4.w;
            }
#pragma unroll
            for (int kk = 0; kk < 4; kk++) {
                float4 w4 = *reinterpret_cast<const float4*>(&Ws[(k4 + kk) * D + c * 4]);
#pragma unroll
                for (int i = 0; i < 8; i++) {
                    acc[i][0] += xs[i][kk] * w4.x;
                    acc[i][1] += xs[i][kk] * w4.y;
                    acc[i][2] += xs[i][kk] * w4.z;
                    acc[i][3] += xs[i][kk] * w4.w;
                }
            }
        }
        __syncthreads();
    }

#pragma unroll
    for (int i = 0; i < 8; i++) {
        int row = row0 + rg * 8 + i;
        if (row < N) {
            float4 o = { acc[i][0], acc[i][1], acc[i][2], acc[i][3] };
            *reinterpret_cast<float4*>(&S[(size_t)row * D + c * 4]) = o;
        }
    }
}

// ---------------- CSR build ----------------
__global__ void hist_kernel(const int* __restrict__ rows, int* __restrict__ counts, int E) {
    int e = blockIdx.x * blockDim.x + threadIdx.x;
    if (e < E) atomicAdd(&counts[rows[e]], 1);
}

__global__ __launch_bounds__(1024) void scan_kernel(const int* __restrict__ counts,
                                                    int* __restrict__ offs, int n) {
    __shared__ int sums[1024];
    const int t = threadIdx.x;
    const int chunk = (n + 1023) / 1024;
    const int begin = t * chunk;
    const int end = min(begin + chunk, n);
    int s = 0;
    for (int i = begin; i < end; i++) s += counts[i];
    sums[t] = s;
    __syncthreads();
    // Hillis-Steele inclusive scan
    for (int off = 1; off < 1024; off <<= 1) {
        int v = (t >= off) ? sums[t - off] : 0;
        __syncthreads();
        sums[t] += v;
        __syncthreads();
    }
    int run = (t == 0) ? 0 : sums[t - 1];
    for (int i = begin; i < end; i++) {
        offs[i] = run;
        run += counts[i];
    }
}

__global__ void fill_kernel(const int* __restrict__ rows, const int* __restrict__ cols,
                            const float* __restrict__ vals, int* __restrict__ cursor,
                            int* __restrict__ col_s, float* __restrict__ val_s, int E) {
    int e = blockIdx.x * blockDim.x + threadIdx.x;
    if (e < E) {
        int r = rows[e];
        int pos = atomicAdd(&cursor[r], 1);
        col_s[pos] = cols[e];
        val_s[pos] = vals[e];
    }
}

// ---------------- SpMM: one wave per output row, no atomics ----------------
__global__ __launch_bounds__(256) void spmm_kernel(const float* __restrict__ S,
                                                   const int* __restrict__ offs,
                                                   const int* __restrict__ counts,
                                                   const int* __restrict__ col_s,
                                                   const float* __restrict__ val_s,
                                                   const float* __restrict__ bias,
                                                   float* __restrict__ out, int N) {
    const int lane = threadIdx.x & 63;
    const int r = blockIdx.x * 4 + (threadIdx.x >> 6);
    if (r >= N) return;
    const float4* Sv = reinterpret_cast<const float4*>(S);

    float4 acc = { 0.f, 0.f, 0.f, 0.f };
    int i = offs[r];
    const int end = i + counts[r];

    for (; i + 1 < end; i += 2) {
        int   c0 = col_s[i],   c1 = col_s[i + 1];
        float v0 = val_s[i],   v1 = val_s[i + 1];
        float4 s0 = Sv[(size_t)c0 * 64 + lane];
        float4 s1 = Sv[(size_t)c1 * 64 + lane];
        acc.x += v0 * s0.x + v1 * s1.x;
        acc.y += v0 * s0.y + v1 * s1.y;
        acc.z += v0 * s0.z + v1 * s1.z;
        acc.w += v0 * s0.w + v1 * s1.w;
    }
    if (i < end) {
        int c0 = col_s[i];
        float v0 = val_s[i];
        float4 s0 = Sv[(size_t)c0 * 64 + lane];
        acc.x += v0 * s0.x; acc.y += v0 * s0.y;
        acc.z += v0 * s0.z; acc.w += v0 * s0.w;
    }

    float4 b = reinterpret_cast<const float4*>(bias)[lane];
    float4 o = { acc.x + b.x, acc.y + b.y, acc.z + b.z, acc.w + b.w };
    reinterpret_cast<float4*>(out)[(size_t)r * 64 + lane] = o;
}

// ---------------- Fallback: atomic scatter (if ws too small for CSR) ----------------
__global__ void init_out_kernel(const float* __restrict__ bias, float* __restrict__ out, int N) {
    int idx = blockIdx.x * blockDim.x + threadIdx.x;  // over N*64 float4s
    if (idx < N * 64) {
        reinterpret_cast<float4*>(out)[idx] = reinterpret_cast<const float4*>(bias)[idx & 63];
    }
}

__global__ void atomic_spmm_kernel(const float* __restrict__ S, const int* __restrict__ rows,
                                   const int* __restrict__ cols, const float* __restrict__ vals,
                                   float* __restrict__ out, int E) {
    const int lane = threadIdx.x & 63;
    const int e = blockIdx.x * 4 + (threadIdx.x >> 6);
    if (e >= E) return;
    int c = cols[e], r = rows[e];
    float v = vals[e];
    float4 s = reinterpret_cast<const float4*>(S)[(size_t)c * 64 + lane];
    float* o = &out[(size_t)r * D + lane * 4];
    atomicAdd(o + 0, v * s.x);
    atomicAdd(o + 1, v * s.y);
    atomicAdd(o + 2, v * s.z);
    atomicAdd(o + 3, v * s.w);
}

extern "C" void kernel_launch(void* const* d_in, const int* in_sizes, int n_in,
                              void* d_out, int out_size, void* d_ws, size_t ws_size,
                              hipStream_t stream) {
    const float* X     = (const float*)d_in[0];
    const float* W     = (const float*)d_in[1];
    const float* bias  = (const float*)d_in[2];
    const float* evals = (const float*)d_in[3];
    const int*   erow  = (const int*)d_in[4];
    const int*   ecol  = (const int*)d_in[5];
    float* out = (float*)d_out;

    const int N = in_sizes[0] / D;
    const int E = in_sizes[3];

    char* ws = (char*)d_ws;
    const size_t supp_bytes = (size_t)N * D * sizeof(float);
    float* S = (float*)ws;
    size_t off = supp_bytes;
    const size_t csr_need = supp_bytes + 3 * (size_t)N * sizeof(int)
                          + (size_t)E * (sizeof(int) + sizeof(float));

    // 1. GEMM: support = X @ W
    gemm_kernel<<<(N + BM - 1) / BM, 256, 0, stream>>>(X, W, S, N);

    if (ws_size >= csr_need) {
        int* counts = (int*)(ws + off); off += (size_t)N * sizeof(int);
        int* offs   = (int*)(ws + off); off += (size_t)N * sizeof(int);
        int* cursor = (int*)(ws + off); off += (size_t)N * sizeof(int);
        int* col_s  = (int*)(ws + off); off += (size_t)E * sizeof(int);
        float* val_s = (float*)(ws + off);

        hipMemsetAsync(counts, 0, (size_t)N * sizeof(int), stream);
        hist_kernel<<<(E + 255) / 256, 256, 0, stream>>>(erow, counts, E);
        scan_kernel<<<1, 1024, 0, stream>>>(counts, offs, N);
        hipMemcpyAsync(cursor, offs, (size_t)N * sizeof(int),
                       hipMemcpyDeviceToDevice, stream);
        fill_kernel<<<(E + 255) / 256, 256, 0, stream>>>(erow, ecol, evals, cursor,
                                                         col_s, val_s, E);
        spmm_kernel<<<(N + 3) / 4, 256, 0, stream>>>(S, offs, counts, col_s, val_s,
                                                     bias, out, N);
    } else {
        // fallback: bias-init + per-edge atomics
        init_out_kernel<<<(N * 64 + 255) / 256, 256, 0, stream>>>(bias, out, N);
        atomic_spmm_kernel<<<(E + 3) / 4, 256, 0, stream>>>(S, ecol, erow, evals, out, E);
    }
}

// Round 2
// 689.008 us; speedup vs baseline: 1.6381x; 1.6381x over previous
//
#include <hip/hip_runtime.h>

#define D 256
#define GBM 128          // gemm rows per block (8 waves x 16)
#define WT_PITCH 264     // bf16 elements per LDS row (256 + 8 pad, keeps 16B align, 2-way banks)

using bf16x8 = __attribute__((ext_vector_type(8))) short;
using f32x4  = __attribute__((ext_vector_type(4))) float;

static __device__ __forceinline__ unsigned short f2bf(float f) {
    unsigned u = __builtin_bit_cast(unsigned, f);
    return (unsigned short)((u + 0x7fffu + ((u >> 16) & 1u)) >> 16);  // RNE
}
static __device__ __forceinline__ float as_f(unsigned u) {
    return __builtin_bit_cast(float, u);
}

// ---------------- W transpose + bf16 cast: Wt[n][k] = bf16(W[k][n]) ----------------
__global__ void wt_kernel(const float* __restrict__ W, unsigned short* __restrict__ Wt) {
    int idx = blockIdx.x * blockDim.x + threadIdx.x;   // 65536 threads total
    int n = idx & 255, k = idx >> 8;
    Wt[n * 256 + k] = f2bf(W[k * 256 + n]);            // reads coalesced along n
}

// ---------------- GEMM: S(bf16) = X @ W via MFMA, full Wt in LDS ----------------
__global__ __launch_bounds__(512) void gemm_mfma(const float* __restrict__ X,
                                                 const unsigned short* __restrict__ Wt,
                                                 unsigned short* __restrict__ S, int N) {
    __shared__ unsigned short wlds[256 * WT_PITCH];    // 132 KB

    // stage Wt: 8192 chunks of 16B
    for (int c = threadIdx.x; c < 8192; c += 512) {
        int n = c >> 5, kc = c & 31;
        uint4 v = *reinterpret_cast<const uint4*>(Wt + n * 256 + kc * 8);
        *reinterpret_cast<uint4*>(&wlds[n * WT_PITCH + kc * 8]) = v;
    }
    __syncthreads();

    const int lane = threadIdx.x & 63;
    const int wave = threadIdx.x >> 6;
    const int row0 = blockIdx.x * GBM + wave * 16;
    const int l16  = lane & 15;
    const int kgrp = lane >> 4;                        // 0..3
    const int arow = min(row0 + l16, N - 1);
    const float* xp = X + (size_t)arow * 256 + kgrp * 8;

    f32x4 acc[16];
#pragma unroll
    for (int i = 0; i < 16; i++) acc[i] = (f32x4)(0.0f);

#pragma unroll
    for (int ks = 0; ks < 8; ks++) {
        // A fragment: 8 fp32 -> bf16, k = ks*32 + kgrp*8 + j
        float4 a0 = *reinterpret_cast<const float4*>(xp + ks * 32);
        float4 a1 = *reinterpret_cast<const float4*>(xp + ks * 32 + 4);
        bf16x8 af;
        af[0] = (short)f2bf(a0.x); af[1] = (short)f2bf(a0.y);
        af[2] = (short)f2bf(a0.z); af[3] = (short)f2bf(a0.w);
        af[4] = (short)f2bf(a1.x); af[5] = (short)f2bf(a1.y);
        af[6] = (short)f2bf(a1.z); af[7] = (short)f2bf(a1.w);
#pragma unroll
        for (int nt = 0; nt < 16; nt++) {
            // B fragment: B[k][col], col = nt*16+l16, k = ks*32 + kgrp*8 + j  (Wt row-contig)
            bf16x8 bf = *reinterpret_cast<const bf16x8*>(
                &wlds[(nt * 16 + l16) * WT_PITCH + ks * 32 + kgrp * 8]);
            acc[nt] = __builtin_amdgcn_mfma_f32_16x16x32_bf16(af, bf, acc[nt], 0, 0, 0);
        }
    }

    // C/D layout: col = lane&15, row = (lane>>4)*4 + reg
#pragma unroll
    for (int nt = 0; nt < 16; nt++) {
#pragma unroll
        for (int j = 0; j < 4; j++) {
            int r = row0 + kgrp * 4 + j;
            if (r < N) S[(size_t)r * 256 + nt * 16 + l16] = f2bf(acc[nt][j]);
        }
    }
}

// ---------------- CSR build ----------------
__global__ void hist_kernel(const int* __restrict__ rows, int* __restrict__ counts, int E) {
    int e = blockIdx.x * blockDim.x + threadIdx.x;
    if (e < E) atomicAdd(&counts[rows[e]], 1);
}

// streaming block-scan, coalesced, shfl-based (single block, 1024 threads)
__global__ __launch_bounds__(1024) void scan_kernel(const int* __restrict__ counts,
                                                    int* __restrict__ offs, int n) {
    __shared__ int wsum[16];
    const int t = threadIdx.x, lane = t & 63, w = t >> 6;
    int carry = 0;
    for (int base = 0; base < n; base += 1024) {
        int i = base + t;
        int x = (i < n) ? counts[i] : 0;
        int s = x;
#pragma unroll
        for (int d = 1; d < 64; d <<= 1) {
            int y = __shfl_up(s, d);
            if (lane >= d) s += y;
        }
        if (lane == 63) wsum[w] = s;
        __syncthreads();
        if (w == 0) {
            int ws = (lane < 16) ? wsum[lane] : 0;
#pragma unroll
            for (int d = 1; d < 16; d <<= 1) {
                int y = __shfl_up(ws, d);
                if (lane >= d) ws += y;
            }
            if (lane < 16) wsum[lane] = ws;
        }
        __syncthreads();
        int wexcl = (w == 0) ? 0 : wsum[w - 1];
        if (i < n) offs[i] = carry + wexcl + s - x;   // exclusive
        carry += wsum[15];
        __syncthreads();                              // protect wsum for next iter
    }
}

__global__ void fill_kernel(const int* __restrict__ rows, const int* __restrict__ cols,
                            const float* __restrict__ vals, int* __restrict__ cursor,
                            int2* __restrict__ cv, int E) {
    int e = blockIdx.x * blockDim.x + threadIdx.x;
    if (e < E) {
        int r = rows[e];
        int pos = atomicAdd(&cursor[r], 1);
        int2 p; p.x = cols[e]; p.y = __float_as_int(vals[e]);
        cv[pos] = p;
    }
}

// ---------------- SpMM: wave per row, bf16 gathers, no atomics ----------------
__global__ __launch_bounds__(256) void spmm_kernel(const unsigned short* __restrict__ S,
                                                   const int* __restrict__ offs,
                                                   const int* __restrict__ counts,
                                                   const int2* __restrict__ cv,
                                                   const float* __restrict__ bias,
                                                   float* __restrict__ out, int N) {
    const int lane = threadIdx.x & 63;
    const int r = blockIdx.x * 4 + (threadIdx.x >> 6);
    if (r >= N) return;
    const char* Sb = reinterpret_cast<const char*>(S);

    float4 acc = { 0.f, 0.f, 0.f, 0.f };
    int i = offs[r];
    const int end = i + counts[r];

#define GATHER(c, v)                                                              \
    {                                                                             \
        uint2 sv = *reinterpret_cast<const uint2*>(Sb + ((size_t)(c) << 9) + (lane << 3)); \
        acc.x += (v) * as_f(sv.x << 16);                                          \
        acc.y += (v) * as_f(sv.x & 0xffff0000u);                                  \
        acc.z += (v) * as_f(sv.y << 16);                                          \
        acc.w += (v) * as_f(sv.y & 0xffff0000u);                                  \
    }

    for (; i + 3 < end; i += 4) {
        int2 e0 = cv[i], e1 = cv[i + 1], e2 = cv[i + 2], e3 = cv[i + 3];
        GATHER(e0.x, as_f((unsigned)e0.y));
        GATHER(e1.x, as_f((unsigned)e1.y));
        GATHER(e2.x, as_f((unsigned)e2.y));
        GATHER(e3.x, as_f((unsigned)e3.y));
    }
    for (; i < end; i++) {
        int2 e0 = cv[i];
        GATHER(e0.x, as_f((unsigned)e0.y));
    }
#undef GATHER

    float4 b = reinterpret_cast<const float4*>(bias)[lane];
    float4 o = { acc.x + b.x, acc.y + b.y, acc.z + b.z, acc.w + b.w };
    reinterpret_cast<float4*>(out)[(size_t)r * 64 + lane] = o;
}

extern "C" void kernel_launch(void* const* d_in, const int* in_sizes, int n_in,
                              void* d_out, int out_size, void* d_ws, size_t ws_size,
                              hipStream_t stream) {
    const float* X     = (const float*)d_in[0];
    const float* W     = (const float*)d_in[1];
    const float* bias  = (const float*)d_in[2];
    const float* evals = (const float*)d_in[3];
    const int*   erow  = (const int*)d_in[4];
    const int*   ecol  = (const int*)d_in[5];
    float* out = (float*)d_out;

    const int N = in_sizes[0] / D;
    const int E = in_sizes[3];

    char* ws = (char*)d_ws;
    size_t off = 0;
    unsigned short* S  = (unsigned short*)(ws + off); off += (size_t)N * D * sizeof(unsigned short);
    unsigned short* Wt = (unsigned short*)(ws + off); off += (size_t)D * D * sizeof(unsigned short);
    int* counts = (int*)(ws + off); off += (size_t)N * sizeof(int);
    int* offs   = (int*)(ws + off); off += (size_t)N * sizeof(int);
    int* cursor = (int*)(ws + off); off += (size_t)N * sizeof(int);
    int2* cv    = (int2*)(ws + off); off += (size_t)E * sizeof(int2);

    // 1. Wt = bf16(W^T)
    wt_kernel<<<(D * D) / 256, 256, 0, stream>>>(W, Wt);
    // 2. S = bf16(X @ W) via MFMA
    gemm_mfma<<<(N + GBM - 1) / GBM, 512, 0, stream>>>(X, Wt, S, N);
    // 3. CSR build
    hipMemsetAsync(counts, 0, (size_t)N * sizeof(int), stream);
    hist_kernel<<<(E + 255) / 256, 256, 0, stream>>>(erow, counts, E);
    scan_kernel<<<1, 1024, 0, stream>>>(counts, offs, N);
    hipMemcpyAsync(cursor, offs, (size_t)N * sizeof(int), hipMemcpyDeviceToDevice, stream);
    fill_kernel<<<(E + 255) / 256, 256, 0, stream>>>(erow, ecol, evals, cursor, cv, E);
    // 4. SpMM + bias
    spmm_kernel<<<(N + 3) / 4, 256, 0, stream>>>(S, offs, counts, cv, bias, out, N);
}